// Round 1
// baseline (3266.301 us; speedup 1.0000x reference)
//
#include <hip/hip_runtime.h>
#include <math.h>

// Problem constants
#define NBATCH 128
#define NTIME  256
#define NCH    512      // nC (feature channels)
#define NH     512      // hidden size
#define NSTEPS 32
#define NOUT   96       // num_classes - 1
#define MTOT   32768    // NBATCH*NTIME

__device__ __forceinline__ float fast_tanh(float x) {
    x = fminf(fmaxf(x, -30.f), 30.f);
    float u = __expf(2.f * x);
    return (u - 1.f) / (u + 1.f);
}
__device__ __forceinline__ float fast_sigmoid(float x) {
    x = fminf(fmaxf(x, -30.f), 30.f);
    return 1.f / (1.f + __expf(-x));
}
__device__ __forceinline__ float wave_reduce_sum(float s) {
    #pragma unroll
    for (int off = 32; off; off >>= 1) s += __shfl_xor(s, off, 64);
    return s;
}

// ---------------------------------------------------------------------------
// feats_proj[m][h] = sum_k feats[k*32768 + m] * Wi2h[h*512 + k]
// m = b*NTIME + t. A is K-major (m contiguous) -> coalesced; B rows k-contiguous.
// BM=128, BN=128, BK=16, 256 threads, 8x8 per thread.
__global__ __launch_bounds__(256) void k_fp_gemm(const float* __restrict__ feats,
                                                 const float* __restrict__ Wi2h,
                                                 float* __restrict__ fp) {
    __shared__ float As[16][128];
    __shared__ float Bs[16][132];
    const int m0 = (blockIdx.x & 255) * 128;
    const int n0 = (blockIdx.x >> 8) * 128;
    const int tid = threadIdx.x;
    const int tx = tid & 15, ty = tid >> 4;
    float acc[8][8] = {};
    for (int k0 = 0; k0 < NCH; k0 += 16) {
        #pragma unroll
        for (int i = 0; i < 2; ++i) {
            int f4 = tid + i * 256;                 // 512 float4 along m
            int kk = f4 >> 5, mm4 = (f4 & 31) << 2;
            *(float4*)(&As[kk][mm4]) =
                *(const float4*)(feats + (size_t)(k0 + kk) * MTOT + m0 + mm4);
        }
        #pragma unroll
        for (int i = 0; i < 2; ++i) {
            int f4 = tid + i * 256;                 // 512 float4 along k (transposed store)
            int nn = f4 >> 2, kq = (f4 & 3) << 2;
            float4 v = *(const float4*)(Wi2h + (size_t)(n0 + nn) * NCH + k0 + kq);
            Bs[kq + 0][nn] = v.x; Bs[kq + 1][nn] = v.y;
            Bs[kq + 2][nn] = v.z; Bs[kq + 3][nn] = v.w;
        }
        __syncthreads();
        #pragma unroll
        for (int kk = 0; kk < 16; ++kk) {
            float a[8], b[8];
            *(float4*)(a)     = *(const float4*)(&As[kk][ty * 8]);
            *(float4*)(a + 4) = *(const float4*)(&As[kk][ty * 8 + 4]);
            *(float4*)(b)     = *(const float4*)(&Bs[kk][tx * 8]);
            *(float4*)(b + 4) = *(const float4*)(&Bs[kk][tx * 8 + 4]);
            #pragma unroll
            for (int i = 0; i < 8; ++i)
                #pragma unroll
                for (int j = 0; j < 8; ++j) acc[i][j] += a[i] * b[j];
        }
        __syncthreads();
    }
    #pragma unroll
    for (int i = 0; i < 8; ++i) {
        float* dst = fp + (size_t)(m0 + ty * 8 + i) * NH + n0 + tx * 8;
        *(float4*)(dst)     = *(float4*)(&acc[i][0]);
        *(float4*)(dst + 4) = *(float4*)(&acc[i][4]);
    }
}

// ---------------------------------------------------------------------------
// Skinny GEMM: C[m][n0+tx] (+bias) = sum_k A[m][k] * W[n][k], M=128, K=512.
// For the gates GEMM, N=3072 is split: n<Nsplit uses (A0,W0,b0), else (A1,W1,b1).
// BM=128(all of M), BN=16, BK=32. 256 threads, 8 outputs/thread.
__global__ __launch_bounds__(256) void k_skinny(const float* __restrict__ A0,
                                                const float* __restrict__ A1,
                                                const float* __restrict__ W0,
                                                const float* __restrict__ W1,
                                                const float* __restrict__ b0,
                                                const float* __restrict__ b1,
                                                float* __restrict__ C,
                                                int Nsplit, int ldc) {
    __shared__ float As[32][128];
    __shared__ float Bs[32][17];
    const int n0 = blockIdx.x * 16;
    const float* A    = (n0 < Nsplit) ? A0 : A1;
    const float* W    = (n0 < Nsplit) ? W0 : W1;
    const float* bias = (n0 < Nsplit) ? b0 : b1;
    const int nb = (n0 < Nsplit) ? n0 : n0 - Nsplit;
    const int tid = threadIdx.x;
    const int tx = tid & 15, ty = tid >> 4;
    float acc[8] = {};
    for (int k0 = 0; k0 < 512; k0 += 32) {
        #pragma unroll
        for (int i = 0; i < 4; ++i) {
            int f4 = tid + i * 256;                 // 1024 float4 (128 rows x 8)
            int mm = f4 >> 3, kq = (f4 & 7) << 2;
            float4 v = *(const float4*)(A + (size_t)mm * 512 + k0 + kq);
            As[kq + 0][mm] = v.x; As[kq + 1][mm] = v.y;
            As[kq + 2][mm] = v.z; As[kq + 3][mm] = v.w;
        }
        if (tid < 128) {
            int nn = tid >> 3, kq = (tid & 7) << 2;
            float4 v = *(const float4*)(W + (size_t)(nb + nn) * 512 + k0 + kq);
            Bs[kq + 0][nn] = v.x; Bs[kq + 1][nn] = v.y;
            Bs[kq + 2][nn] = v.z; Bs[kq + 3][nn] = v.w;
        }
        __syncthreads();
        #pragma unroll
        for (int kk = 0; kk < 32; ++kk) {
            float bv = Bs[kk][tx];
            float a[8];
            *(float4*)(a)     = *(const float4*)(&As[kk][ty * 8]);
            *(float4*)(a + 4) = *(const float4*)(&As[kk][ty * 8 + 4]);
            #pragma unroll
            for (int i = 0; i < 8; ++i) acc[i] += a[i] * bv;
        }
        __syncthreads();
    }
    float bb = bias[nb + tx];
    #pragma unroll
    for (int i = 0; i < 8; ++i) {
        C[(size_t)(ty * 8 + i) * ldc + n0 + tx] = acc[i] + bb;
    }
}

// ---------------------------------------------------------------------------
// e[b][t] = sum_h tanh(fp[b][t][h] + hp[b][h]) * wscore[h]
// grid 1024: b = blk>>3, t-range of 32. Wave per t, lane owns 8 h's.
__global__ __launch_bounds__(256) void k_e(const float* __restrict__ fp,
                                           const float* __restrict__ hp,
                                           const float* __restrict__ wscore,
                                           float* __restrict__ e) {
    const int b = blockIdx.x >> 3;
    const int t0 = (blockIdx.x & 7) * 32;
    const int tid = threadIdx.x;
    const int lane = tid & 63, w = tid >> 6;
    // each lane's fixed h-slice: h = lane*8 .. lane*8+7
    float4 h0 = *(const float4*)(hp + (size_t)b * NH + lane * 8);
    float4 h1 = *(const float4*)(hp + (size_t)b * NH + lane * 8 + 4);
    float4 w0 = *(const float4*)(wscore + lane * 8);
    float4 w1 = *(const float4*)(wscore + lane * 8 + 4);
    for (int it = 0; it < 8; ++it) {
        int t = t0 + w * 8 + it;
        const float4* p = (const float4*)(fp + (size_t)(b * NTIME + t) * NH + lane * 8);
        float4 v0 = p[0], v1 = p[1];
        float s = fast_tanh(v0.x + h0.x) * w0.x + fast_tanh(v0.y + h0.y) * w0.y +
                  fast_tanh(v0.z + h0.z) * w0.z + fast_tanh(v0.w + h0.w) * w0.w +
                  fast_tanh(v1.x + h1.x) * w1.x + fast_tanh(v1.y + h1.y) * w1.y +
                  fast_tanh(v1.z + h1.z) * w1.z + fast_tanh(v1.w + h1.w) * w1.w;
        s = wave_reduce_sum(s);
        if (lane == 0) e[b * NTIME + t] = s;
    }
}

// ---------------------------------------------------------------------------
// In-place softmax over t (256) per batch row. grid 128, 256 threads.
__global__ __launch_bounds__(256) void k_sm(float* __restrict__ e) {
    const int b = blockIdx.x;
    const int tid = threadIdx.x;
    __shared__ float red[4];
    float v = e[b * NTIME + tid];
    float m = v;
    #pragma unroll
    for (int off = 32; off; off >>= 1) m = fmaxf(m, __shfl_xor(m, off, 64));
    if ((tid & 63) == 0) red[tid >> 6] = m;
    __syncthreads();
    m = fmaxf(fmaxf(red[0], red[1]), fmaxf(red[2], red[3]));
    float ex = __expf(v - m);
    __syncthreads();
    float s = wave_reduce_sum(ex);
    if ((tid & 63) == 0) red[tid >> 6] = s;
    __syncthreads();
    s = red[0] + red[1] + red[2] + red[3];
    e[b * NTIME + tid] = ex / s;
}

// ---------------------------------------------------------------------------
// ctx[b][c] = sum_t feats[c][b][t] * alpha[b][t]. grid 4096: b = blk>>5, 16 c's.
__global__ __launch_bounds__(256) void k_ctx(const float* __restrict__ feats,
                                             const float* __restrict__ alpha,
                                             float* __restrict__ ctx) {
    __shared__ float als[256];
    const int b = blockIdx.x >> 5;
    const int c0 = (blockIdx.x & 31) * 16;
    const int tid = threadIdx.x;
    als[tid] = alpha[b * NTIME + tid];
    __syncthreads();
    const int lane = tid & 63, w = tid >> 6;
    float4 av = ((const float4*)als)[lane];
    for (int it = 0; it < 4; ++it) {
        int c = c0 + w * 4 + it;
        float4 f = *(const float4*)(feats + (size_t)(c * NBATCH + b) * NTIME + lane * 4);
        float s = f.x * av.x + f.y * av.y + f.z * av.z + f.w * av.w;
        s = wave_reduce_sum(s);
        if (lane == 0) ctx[b * NH + c] = s;
    }
}

// ---------------------------------------------------------------------------
// GRU combine. g = [gi(r,z,n) | gh(r,z,n)] as [128][3072]. grid 256x256.
__global__ __launch_bounds__(256) void k_comb(const float* __restrict__ g,
                                              const float* __restrict__ hprev,
                                              float* __restrict__ hnew) {
    const int idx = blockIdx.x * 256 + threadIdx.x;     // 65536 total
    const int b = idx >> 9, n = idx & 511;
    const float* gb = g + (size_t)b * 3072;
    float ir = gb[n],        iz = gb[n + 512],  in_ = gb[n + 1024];
    float hr = gb[n + 1536], hz = gb[n + 2048], hn  = gb[n + 2560];
    float r = fast_sigmoid(ir + hr);
    float z = fast_sigmoid(iz + hz);
    float ng = fast_tanh(in_ + r * hn);
    hnew[idx] = (1.f - z) * ng + z * hprev[idx];
}

// ---------------------------------------------------------------------------
// probs[(b*32+s)][n] = sum_k hid[(s+1)][b][k] * Wgen[n][k] + bgen[n]
// M=4096, N=96, K=512. BM=32, BK=32. grid 128, 256 threads, 4x3 per thread.
__global__ __launch_bounds__(256) void k_gen(const float* __restrict__ hid,
                                             const float* __restrict__ Wgen,
                                             const float* __restrict__ bgen,
                                             float* __restrict__ out) {
    __shared__ float As[32][36];
    __shared__ float Bs[32][97];
    const int m0 = blockIdx.x * 32;
    const int tid = threadIdx.x;
    const int tx = tid & 31, ty = tid >> 5;     // tx: 3 n's, ty: 4 m's
    float acc[4][3] = {};
    for (int k0 = 0; k0 < 512; k0 += 32) {
        {
            int mm = tid >> 3, kq = (tid & 7) << 2;
            int m = m0 + mm, s = m & 31, b = m >> 5;
            float4 v = *(const float4*)(hid + (size_t)(s + 1) * 65536 + b * 512 + k0 + kq);
            *(float4*)(&As[mm][kq]) = v;
        }
        #pragma unroll
        for (int i = 0; i < 3; ++i) {
            int f4 = tid + i * 256;             // 768 float4 (96 rows x 8)
            int nn = f4 >> 3, kq = (f4 & 7) << 2;
            float4 v = *(const float4*)(Wgen + (size_t)nn * 512 + k0 + kq);
            Bs[kq + 0][nn] = v.x; Bs[kq + 1][nn] = v.y;
            Bs[kq + 2][nn] = v.z; Bs[kq + 3][nn] = v.w;
        }
        __syncthreads();
        #pragma unroll
        for (int kk = 0; kk < 32; ++kk) {
            float bv[3];
            #pragma unroll
            for (int j = 0; j < 3; ++j) bv[j] = Bs[kk][tx * 3 + j];
            #pragma unroll
            for (int i = 0; i < 4; ++i) {
                float a = As[ty * 4 + i][kk];
                #pragma unroll
                for (int j = 0; j < 3; ++j) acc[i][j] += a * bv[j];
            }
        }
        __syncthreads();
    }
    #pragma unroll
    for (int i = 0; i < 4; ++i)
        #pragma unroll
        for (int j = 0; j < 3; ++j)
            out[(size_t)(m0 + ty * 4 + i) * NOUT + tx * 3 + j] = acc[i][j] + bgen[tx * 3 + j];
}

// ---------------------------------------------------------------------------
extern "C" void kernel_launch(void* const* d_in, const int* in_sizes, int n_in,
                              void* d_out, int out_size, void* d_ws, size_t ws_size,
                              hipStream_t stream) {
    const float* feats  = (const float*)d_in[0];
    // d_in[1] = text_length (all == NSTEPS), unused
    const float* Wi2h   = (const float*)d_in[2];
    const float* Wh2h   = (const float*)d_in[3];
    const float* bh2h   = (const float*)d_in[4];
    const float* Wscore = (const float*)d_in[5];
    const float* Wih    = (const float*)d_in[6];
    const float* Whh    = (const float*)d_in[7];
    const float* bih    = (const float*)d_in[8];
    const float* bhh    = (const float*)d_in[9];
    const float* Wgen   = (const float*)d_in[10];
    const float* bgen   = (const float*)d_in[11];
    float* out = (float*)d_out;

    // Workspace layout (floats). Total = 19,496,960 floats = 78 MB.
    float* ws  = (float*)d_ws;
    float* fp  = ws;                      // 32768*512   = 16777216
    float* hid = fp + 16777216;           // 33*128*512  = 2162688 (slot 0 = h0 zeros)
    float* hp  = hid + 2162688;           // 65536
    float* e   = hp + 65536;              // 32768 (reused in-place as alpha)
    float* g   = e + 32768;               // 128*3072    = 393216
    float* ctx = g + 393216;              // 65536

    hipMemsetAsync(hid, 0, 65536 * sizeof(float), stream);   // h0 = 0
    k_fp_gemm<<<1024, 256, 0, stream>>>(feats, Wi2h, fp);

    for (int s = 0; s < NSTEPS; ++s) {
        const float* h = hid + (size_t)s * 65536;
        float* hn      = hid + (size_t)(s + 1) * 65536;
        // hp = h @ Wh2h^T + bh2h       (N=512 -> 32 blocks)
        k_skinny<<<32, 256, 0, stream>>>(h, h, Wh2h, Wh2h, bh2h, bh2h, hp, 1 << 30, 512);
        k_e<<<1024, 256, 0, stream>>>(fp, hp, Wscore, e);
        k_sm<<<128, 256, 0, stream>>>(e);
        k_ctx<<<4096, 256, 0, stream>>>(feats, e, ctx);
        // g = [ctx @ Wih^T + bih | h @ Whh^T + bhh]   (N=3072 -> 192 blocks)
        k_skinny<<<192, 256, 0, stream>>>(ctx, h, Wih, Whh, bih, bhh, g, 1536, 3072);
        k_comb<<<256, 256, 0, stream>>>(g, h, hn);
    }
    k_gen<<<128, 256, 0, stream>>>(hid, Wgen, bgen, out);
}